// Round 9
// baseline (2351.972 us; speedup 1.0000x reference)
//
#include <hip/hip_runtime.h>
#include <math.h>

typedef unsigned short u16;
typedef unsigned long long u64;
typedef __attribute__((ext_vector_type(8))) short bf16x8;   // MFMA A/B frag
typedef __attribute__((ext_vector_type(4))) float f32x4;    // MFMA C/D frag

#define T_STEPS 32
#define BSZ     32
#define N_IN    64
#define H       256
#define N_OUT   64
#define ESTRIDE 9984              // rows = 320*31 + 64 (final fresh block)
#define CLAMP_MIN (-2.0f)
#define CLAMP_MAX ( 2.0f)
#define NSL 32                    // tile-slices per sample (32-row tiles)

// ---------------------------------------------------------------------------
// Fragment-packed layout "B" (8B-quad granular):
//   element (row R, k):  RT=R>>4, m=R&15, KC=k>>5, qq=(k&31)>>3, h=(k&7)>>2, v=k&3
//   u16 offset = ((RT*8+KC)*4+qq)*128 + m*8 + h*4 + v
// A/B-frag load for (RT,KC), lane(m,q): contiguous 16B at (((RT*8+KC)*4+q)<<7)+m*8.
// C^T store (operand-swapped mfma): lane's 4 acc values = 8B contiguous.
//
// Fence-free dataflow sync (r8-verified): err rows are BLOCK-PRIVATE (tile j
// owned by block j%NSL; diag tiles written by owner). Cross-block data = only
// rad/hp (device-scope atomics; read via agent-scope atomic loads). Per-sample
// arrival counters order steps. NEW (r9): each block interleaves TWO samples
// (p and p+Bc/2) so every step boundary of one sample hides under a full step
// of the other — removes the ~16 µs/step collective-drain bubble.
// ---------------------------------------------------------------------------

__device__ inline u16 f2bf(float x) {                       // RTNE fp32->bf16
    unsigned u = __builtin_bit_cast(unsigned, x);
    unsigned r = u + 0x7FFFu + ((u >> 16) & 1u);
    return (u16)(r >> 16);
}
__device__ inline float bf2f(short s) {
    return __builtin_bit_cast(float, ((unsigned)(u16)s) << 16);
}

__device__ __forceinline__ void gl_lds16(const u16* g, u16* l) {
    __builtin_amdgcn_global_load_lds(
        (const __attribute__((address_space(1))) unsigned int*)g,
        (__attribute__((address_space(3))) unsigned int*)l,
        16, 0, 0);
}

__device__ __forceinline__ float aload(const float* p) {
    return __hip_atomic_load(p, __ATOMIC_RELAXED, __HIP_MEMORY_SCOPE_AGENT);
}

// stage up to 3 owned tiles of errS into ring slots cur..cur+2
__device__ __forceinline__ void stage3(const u16* errS, u16 (*sbuf)[8192],
                                       int ntiles, int bx, int cur,
                                       int tid, int wave)
{
    #pragma unroll
    for (int j = 0; j < 3; ++j) {
        int tj = bx + j * NSL;
        if (tj < ntiles) {
            const u16* g = errS + (size_t)tj * 8192;
            #pragma unroll
            for (int r = 0; r < 4; ++r)
                gl_lds16(g + r * 2048 + tid * 8,
                         &sbuf[(cur + j) & 3][r * 2048 + wave * 512]);
        }
    }
}

// ---------------------------------------------------------------------------
__global__ void initarr_k(unsigned* arr) {                  // zero arrival ctrs
    arr[threadIdx.x + blockIdx.x * 256] = 0u;
}

// ---------------------------------------------------------------------------
__global__ void transpose_k(const float* __restrict__ src, float* __restrict__ dst,
                            int R, int C)
{
    __shared__ float tile[32][33];
    int bi = blockIdx.y, bj = blockIdx.x;
    int r0 = threadIdx.x >> 5, c = threadIdx.x & 31;
    #pragma unroll
    for (int rr = 0; rr < 4; ++rr) {
        int r = r0 * 4 + rr;
        tile[r][c] = src[(bi * 32 + r) * C + bj * 32 + c];
    }
    __syncthreads();
    #pragma unroll
    for (int rr = 0; rr < 4; ++rr) {
        int r = r0 * 4 + rr;
        dst[(bj * 32 + r) * R + bi * 32 + c] = tile[c][r];
    }
}

// ---------------------------------------------------------------------------
// packPairs: W (R x 256 fp32) -> float2 pairs in layout-B p-order.
// ---------------------------------------------------------------------------
__global__ void packPairs_k(const float* __restrict__ W, float* __restrict__ WP)
{
    int p = blockIdx.x * 256 + threadIdx.x;
    int vb = (p & 1) * 2, hh = (p >> 1) & 1, m = (p >> 2) & 15, qq = (p >> 6) & 3;
    int KC = (p >> 8) & 7, RT = p >> 11;
    int i = RT * 16 + m, k = KC * 32 + qq * 8 + hh * 4 + vb;
    ((float2*)WP)[p] = make_float2(W[(size_t)i * H + k], W[(size_t)i * H + k + 1]);
}

// ---------------------------------------------------------------------------
// packWT: WhhT32 (256x256 fp32) -> bf16 layout-B (static, no lam). grid 128x256.
// ---------------------------------------------------------------------------
__global__ void packWT_k(const float* __restrict__ WT32, u16* __restrict__ WTp)
{
    int p = blockIdx.x * 256 + threadIdx.x;     // p < 32768
    int vb = (p & 1) * 2, hh = (p >> 1) & 1, m = (p >> 2) & 15, qq = (p >> 6) & 3;
    int KC = (p >> 8) & 7, RT = p >> 11;
    int n = RT * 16 + m, k = KC * 32 + qq * 8 + hh * 4 + vb;
    *(unsigned*)&WTp[2 * p] =
          (unsigned)f2bf(WT32[(size_t)n * H + k])
        | ((unsigned)f2bf(WT32[(size_t)n * H + k + 1]) << 16);
}

// ---------------------------------------------------------------------------
// prefresh: fresh rows (rho_t * Wih) for ALL t + fresh-rad baseline + head
// baseline hpX[t] = bias + hx_t @ Wih. grid (T_STEPS, Bc).
// ---------------------------------------------------------------------------
__global__ __launch_bounds__(256) void prefresh_k(
    const float* __restrict__ X, const float* __restrict__ eps,
    const float* __restrict__ Wih, const float* __restrict__ WihP,
    const float* __restrict__ bih, const float* __restrict__ bhh,
    u16* __restrict__ err, float* __restrict__ radT, float* __restrict__ hpX)
{
    __shared__ float rho_s[N_IN], hx_s[N_IN];
    const int t = blockIdx.x, bi = blockIdx.y, tid = threadIdx.x;
    if (tid < N_IN) {
        float x = X[((size_t)t * BSZ + bi) * N_IN + tid], e = eps[bi];
        float lo = fmaxf(x - e, CLAMP_MIN), up = fminf(x + e, CLAMP_MAX);
        rho_s[tid] = 0.5f * (up - lo);
        hx_s[tid]  = 0.5f * (up + lo);
    }
    __syncthreads();

    float s = 0.f, acc = bih[tid] + bhh[tid];
    #pragma unroll 8
    for (int i = 0; i < N_IN; ++i) {
        float w = Wih[(size_t)i * H + tid];
        s   += fabsf(rho_s[i]) * fabsf(w);
        acc += hx_s[i] * w;
    }
    radT[(size_t)t * BSZ * H + (size_t)bi * H + tid] = s;
    hpX [(size_t)t * BSZ * H + (size_t)bi * H + tid] = acc;

    u16* dst = err + (size_t)bi * ESTRIDE * H + (size_t)(20 * t) * 4096; // row 320t
    const float2* wp = (const float2*)WihP;
    #pragma unroll 4
    for (int iter = 0; iter < 32; ++iter) {
        int p = iter * 256 + tid;
        int i = (p >> 11) * 16 + ((p >> 2) & 15);
        float2 w = wp[p];
        float rho = rho_s[i];
        *(unsigned*)&dst[2 * p] =
            (unsigned)f2bf(rho * w.x) | ((unsigned)f2bf(rho * w.y) << 16);
    }
}

// ---------------------------------------------------------------------------
// loop_k: PERSISTENT two-sample-interleaved t-loop. grid (NSL, Bc2) = 512
// blocks = 2/CU co-resident. Block (bx,pb) alternates half-steps between
// samples pb and pb+Bc2; the next half-step's tiles are staged BEFORE the
// current half-step's drain, so boundary bubbles hide under the other
// sample's work. Step body = r8-verified pipeline (4-ring, stage-3-ahead,
// counted vmcnt(32), C^T stores, fence-free arrival counters).
// ---------------------------------------------------------------------------
__global__ __launch_bounds__(256, 2) void loop_k(
    const float* __restrict__ Whh, const float* __restrict__ WhhP,
    const u16* __restrict__ WhhTp,
    float* __restrict__ hpX, float* __restrict__ radT,
    u16* __restrict__ err, unsigned* __restrict__ arrive,
    int b0, int Bc, int Bc2)
{
    __shared__ u16 sbuf[4][8192];            // 4 x 16KB tile ring (shared A/B)
    __shared__ float lam_s[H], de_s[H], hh_s[H];
    const int bx = blockIdx.x, pb = blockIdx.y, tid = threadIdx.x;
    const int wave = tid >> 6, lane = tid & 63;
    const int m = lane & 15, q = lane >> 4;

    int cur = 0;
    { // preamble: stage half-step 0 = (sample pb, t=1), ntiles=2
        const u16* errS = err + (size_t)pb * ESTRIDE * H;
        stage3(errS, sbuf, 2, bx, cur, tid, wave);
    }

    #pragma unroll 1
    for (int h = 0; h < 2 * (T_STEPS - 1); ++h) {
        const int t  = (h >> 1) + 1;
        const int s  = h & 1;
        const int bb = s ? pb + Bc2 : pb;
        const bool act = (bb < Bc);
        const int babs = b0 + bb;
        u16* errS = err + (size_t)bb * ESTRIDE * H;
        const int E_old = t * (N_IN + H);
        const int ntiles = (E_old - H) >> 5;             // 32-row tiles = 10t-8
        const float* hpp  = hpX  + (size_t)(t - 1) * BSZ * H + (size_t)babs * H;
        float*       hpn  = hpX  + (size_t)t       * BSZ * H + (size_t)babs * H;
        const float* radp = radT + (size_t)(t - 1) * BSZ * H + (size_t)babs * H;
        float*       radn = radT + (size_t)t       * BSZ * H + (size_t)babs * H;
        const bool gem = act && (bx < ntiles);

        // B-slab: static bf16 WhhTp frags (L2-hot) — issued before the spin
        bf16x8 bf[4][8];
        if (gem) {
            #pragma unroll
            for (int nt = 0; nt < 4; ++nt)
                #pragma unroll
                for (int kc = 0; kc < 8; ++kc)
                    bf[nt][kc] = *(const bf16x8*)
                        &WhhTp[(size_t)(((((wave * 4 + nt) * 8 + kc) * 4 + q) << 7) + m * 8)];
        }

        // wait for this sample's step t-1 producers (usually satisfied — the
        // other sample's full step ran in between).
        if (act && t > 1) {
            if (tid == 0) {
                const unsigned* a = &arrive[(t - 1) * BSZ + babs];
                while (__hip_atomic_load(a, __ATOMIC_RELAXED,
                                         __HIP_MEMORY_SCOPE_AGENT) < (unsigned)NSL)
                    __builtin_amdgcn_s_sleep(8);
            }
            __builtin_amdgcn_s_barrier();
        }

        if (act) { // coherent rad/hp read (agent-scope atomic loads) + tanh
            float hd = aload(&hpp[tid]), rv = aload(&radp[tid]);
            float lo = hd - rv, up = hd + rv;
            float tl = tanhf(lo), tu = tanhf(up);
            float la = fminf(1.f - tl * tl, 1.f - tu * tu);
            float mu = 0.5f * (tu + tl - la * (up + lo));
            float dd = 0.5f * (tu - tl - la * (up - lo));
            lam_s[tid] = la;
            de_s[tid]  = dd;
            hh_s[tid]  = la * hd + mu;
            asm volatile("s_waitcnt lgkmcnt(0)" ::: "memory");
            __builtin_amdgcn_s_barrier();
        }

        if (gem) {
            // fold lam into B-frags in-register
            #pragma unroll
            for (int nt = 0; nt < 4; ++nt)
                #pragma unroll
                for (int kc = 0; kc < 8; ++kc) {
                    const int k0 = kc * 32 + q * 8;
                    float4 la = *(const float4*)&lam_s[k0];
                    float4 lb = *(const float4*)&lam_s[k0 + 4];
                    bf16x8 w = bf[nt][kc], f;
                    f[0] = (short)f2bf(bf2f(w[0]) * la.x);
                    f[1] = (short)f2bf(bf2f(w[1]) * la.y);
                    f[2] = (short)f2bf(bf2f(w[2]) * la.z);
                    f[3] = (short)f2bf(bf2f(w[3]) * la.w);
                    f[4] = (short)f2bf(bf2f(w[4]) * lb.x);
                    f[5] = (short)f2bf(bf2f(w[5]) * lb.y);
                    f[6] = (short)f2bf(bf2f(w[6]) * lb.z);
                    f[7] = (short)f2bf(bf2f(w[7]) * lb.w);
                    bf[nt][kc] = f;
                }

            float racc[16];
            #pragma unroll
            for (int i = 0; i < 16; ++i) racc[i] = 0.f;

            // this half-step's pre-staged tiles were drained by the previous
            // half-step's final vmcnt(0)+sync; this wait is ~free (covers h=0).
            asm volatile("s_waitcnt vmcnt(0)" ::: "memory");
            __builtin_amdgcn_s_barrier();

            for (int tile = bx; tile < ntiles; tile += NSL) {
                int pf = tile + 3 * NSL;
                if (pf < ntiles) {           // stage 3 tiles ahead
                    const u16* g = errS + (size_t)pf * 8192;
                    #pragma unroll
                    for (int r = 0; r < 4; ++r)
                        gl_lds16(g + r * 2048 + tid * 8,
                                 &sbuf[(cur + 3) & 3][r * 2048 + wave * 512]);
                }

                f32x4 acc[2][4];
                #pragma unroll
                for (int i = 0; i < 2; ++i)
                    #pragma unroll
                    for (int c = 0; c < 4; ++c) acc[i][c] = (f32x4){0.f, 0.f, 0.f, 0.f};

                #pragma unroll
                for (int kc = 0; kc < 8; ++kc) {
                    bf16x8 af[2];
                    #pragma unroll
                    for (int rt = 0; rt < 2; ++rt)
                        af[rt] = *(const bf16x8*)
                            &sbuf[cur][(((rt * 8 + kc) * 4 + q) << 7) + m * 8];
                    #pragma unroll
                    for (int nt = 0; nt < 4; ++nt)
                        #pragma unroll
                        for (int rt = 0; rt < 2; ++rt)   // A=WT, B=err -> C^T
                            acc[rt][nt] = __builtin_amdgcn_mfma_f32_16x16x32_bf16(
                                bf[nt][kc], af[rt], acc[rt][nt], 0, 0, 0);
                }

                // C^T store: lane holds err-row r = rt*16+m, n = NT*16+q*4+v
                #pragma unroll
                for (int rt = 0; rt < 2; ++rt) {
                    const size_t rowbase = (size_t)(tile * 2 + rt) * 4096;
                    #pragma unroll
                    for (int nt = 0; nt < 4; ++nt) {
                        f32x4 v = acc[rt][nt];
                        racc[nt * 4 + 0] += fabsf(v[0]);
                        racc[nt * 4 + 1] += fabsf(v[1]);
                        racc[nt * 4 + 2] += fabsf(v[2]);
                        racc[nt * 4 + 3] += fabsf(v[3]);
                        unsigned lo = (unsigned)f2bf(v[0]) | ((unsigned)f2bf(v[1]) << 16);
                        unsigned hi = (unsigned)f2bf(v[2]) | ((unsigned)f2bf(v[3]) << 16);
                        const int NT  = wave * 4 + nt;
                        const int kcs = NT >> 1;
                        const int qq  = (NT & 1) * 2 + (q >> 1);
                        const size_t off16 = rowbase
                            + (size_t)(((kcs * 4 + qq) << 7) + m * 8 + (q & 1) * 4);
                        *(u64*)&errS[off16] = ((u64)hi << 32) | lo;
                    }
                }
                // vmcnt(32): keeps 2 iters of stage + ~3 iters of stores in
                // flight; drains exactly the stage consumed NEXT iteration.
                asm volatile("s_waitcnt vmcnt(32)" ::: "memory");
                __builtin_amdgcn_s_barrier();
                cur = (cur + 1) & 3;
            }

            // rad: reduce over 16 m-lanes, one atomic per n from m==0 lanes
            #pragma unroll
            for (int i = 0; i < 16; ++i) {
                float v = racc[i];
                v += __shfl_xor(v, 1);
                v += __shfl_xor(v, 2);
                v += __shfl_xor(v, 4);
                v += __shfl_xor(v, 8);
                if (m == 0) {
                    int nt = i >> 2, vv = i & 3;
                    atomicAdd(&radn[wave * 64 + nt * 16 + q * 4 + vv], v);
                }
            }
        }

        // stage NEXT half-step's tiles now — their latency hides under this
        // half-step's epilogue + drain + next tanh (block-private data).
        {
            int hn = h + 1;
            if (hn < 2 * (T_STEPS - 1)) {
                int tn = (hn >> 1) + 1, sn = hn & 1;
                int bbn = sn ? pb + Bc2 : pb;
                if (bbn < Bc) {
                    int ntn = (tn * (N_IN + H) - H) >> 5;
                    stage3(err + (size_t)bbn * ESTRIDE * H, sbuf, ntn,
                           bx, cur, tid, wave);
                }
            }
        }

        if (act) {
            // diag tiles OWNED by this block (dt%NSL==bx) — block-private
            const int dtile0 = 10 * t - 8;
            const float2* wp = (const float2*)WhhP;
            #pragma unroll
            for (int i = 0; i < 8; ++i) {
                int dt = dtile0 + i;
                if ((dt & (NSL - 1)) == bx) {
                    #pragma unroll
                    for (int rt2 = 0; rt2 < 2; ++rt2) {
                        int RTw = i * 2 + rt2;           // Whh row-tile
                        u16* dst2 = errS + (size_t)(dt * 2 + rt2) * 4096;
                        const float2* wp2 = wp + (size_t)RTw * 2048;
                        #pragma unroll
                        for (int iter = 0; iter < 8; ++iter) {
                            int p = iter * 256 + tid;
                            int mm = (p >> 2) & 15;
                            float dv = de_s[RTw * 16 + mm];
                            float2 w = wp2[p];
                            *(unsigned*)&dst2[2 * p] =
                                (unsigned)f2bf(dv * w.x) | ((unsigned)f2bf(dv * w.y) << 16);
                        }
                    }
                }
            }
            // fused diag-rad + head-partial GEMV over this block's 8 Whh rows
            float ss = 0.f, hacc = 0.f;
            #pragma unroll
            for (int ii = 0; ii < 8; ++ii) {
                int i = bx * 8 + ii;
                float w = Whh[(size_t)i * H + tid];
                ss   += fabsf(de_s[i]) * fabsf(w);
                hacc += hh_s[i] * w;
            }
            atomicAdd(&radn[tid], ss);
            atomicAdd(&hpn[tid], hacc);
        }

        // publish: atomics acked at coherence point, then arrive++ (also
        // drains next half-step's stages -> its pre-gemm wait is free).
        asm volatile("s_waitcnt vmcnt(0)" ::: "memory");
        __syncthreads();
        if (act && tid == 0)
            __hip_atomic_fetch_add(&arrive[t * BSZ + babs], 1u,
                                   __ATOMIC_RELAXED, __HIP_MEMORY_SCOPE_AGENT);
    }
}

// ---------------------------------------------------------------------------
__global__ __launch_bounds__(256) void tanh_final_k(
    const float* __restrict__ hp, const float* __restrict__ rad,
    float* __restrict__ lam, float* __restrict__ de, float* __restrict__ head_h)
{
    const int b = blockIdx.x, h = threadIdx.x;
    float hd = hp[b * H + h], r = rad[b * H + h];
    float l = hd - r, u = hd + r;
    float tl = tanhf(l), tu = tanhf(u);
    float la = fminf(1.f - tl * tl, 1.f - tu * tu);
    float mu = 0.5f * (tu + tl - la * (u + l));
    float dd = 0.5f * (tu - tl - la * (u - l));
    lam[b * H + h] = la;
    de[b * H + h]  = dd;
    head_h[b * H + h] = la * hd + mu;
}

// ---------------------------------------------------------------------------
// pack WoT frag-packed (layout B), lam folded. grid Bc x 256.
// ---------------------------------------------------------------------------
__global__ __launch_bounds__(256) void packWoT_k(
    const float* __restrict__ WoT32, const float* __restrict__ lam,
    u16* __restrict__ WoTp)
{
    const int b = blockIdx.x, tid = threadIdx.x;
    __shared__ float lam_s[H];
    lam_s[tid] = lam[b * H + tid];
    __syncthreads();
    u16* dst = WoTp + (size_t)b * N_OUT * H;
    #pragma unroll 4
    for (int iter = 0; iter < 32; ++iter) {
        int p = iter * 256 + tid;
        int vb = (p & 1) * 2, hh = (p >> 1) & 1, m = (p >> 2) & 15, qq = (p >> 6) & 3;
        int KC = (p >> 8) & 7, RT = p >> 11;   // RT < 4
        int n = RT * 16 + m, k = KC * 32 + qq * 8 + hh * 4 + vb;
        *(unsigned*)&dst[2 * p] =
              (unsigned)f2bf(lam_s[k]     * WoT32[(size_t)n * H + k])
            | ((unsigned)f2bf(lam_s[k + 1] * WoT32[(size_t)n * H + k + 1]) << 16);
    }
}

// ---------------------------------------------------------------------------
__global__ void head_out_k(
    const float* __restrict__ head_h, const float* __restrict__ de,
    const float* __restrict__ Wo, const float* __restrict__ bo,
    float* __restrict__ head_out, float* __restrict__ rad_out)
{
    const int b = blockIdx.x, o = threadIdx.x;
    float acc = bo[o], accR = 0.f;
    #pragma unroll 4
    for (int j = 0; j < H; ++j) {
        float w = Wo[j * N_OUT + o];
        acc  += head_h[b * H + j] * w;
        accR += fabsf(de[b * H + j] * w);
    }
    head_out[b * N_OUT + o] = acc;
    rad_out[b * N_OUT + o]  = accR;
}

// ---------------------------------------------------------------------------
// final radius: rad_out += sum_rows |err @ WoTp^T| over all ESTRIDE rows.
// ---------------------------------------------------------------------------
__global__ __launch_bounds__(256) void gemm_out_k(
    const u16* __restrict__ err, const u16* __restrict__ WoTp,
    float* __restrict__ rad_out)
{
    __shared__ float rad_s[N_OUT];
    const int b = blockIdx.y, row0 = blockIdx.x * 256, tid = threadIdx.x;
    const int wave = tid >> 6, lane = tid & 63;
    const int m = lane & 15, q = lane >> 4;
    const u16* errB = err + (size_t)b * ESTRIDE * H;
    const u16* Wb   = WoTp + (size_t)b * N_OUT * H;

    if (tid < N_OUT) rad_s[tid] = 0.f;
    __syncthreads();

    f32x4 acc[4][4];
    #pragma unroll
    for (int i = 0; i < 4; ++i)
        #pragma unroll
        for (int c = 0; c < 4; ++c) acc[i][c] = (f32x4){0.f, 0.f, 0.f, 0.f};

    const int tile0 = (row0 >> 4) + wave * 4;
    #pragma unroll
    for (int kc = 0; kc < 8; ++kc) {
        bf16x8 af[4], bw[4];
        #pragma unroll
        for (int rt = 0; rt < 4; ++rt)
            af[rt] = *(const bf16x8*)
                &errB[(size_t)(((((tile0 + rt) * 8 + kc) * 4 + q) << 7) + m * 8)];
        #pragma unroll
        for (int nt = 0; nt < 4; ++nt)
            bw[nt] = *(const bf16x8*)
                &Wb[(size_t)((((nt * 8 + kc) * 4 + q) << 7) + m * 8)];
        #pragma unroll
        for (int nt = 0; nt < 4; ++nt)
            #pragma unroll
            for (int rt = 0; rt < 4; ++rt)
                acc[rt][nt] = __builtin_amdgcn_mfma_f32_16x16x32_bf16(
                    af[rt], bw[nt], acc[rt][nt], 0, 0, 0);
    }
    #pragma unroll
    for (int nt = 0; nt < 4; ++nt) {
        float s = 0.f;
        #pragma unroll
        for (int rt = 0; rt < 4; ++rt)
            #pragma unroll
            for (int r = 0; r < 4; ++r) s += fabsf(acc[rt][nt][r]);
        atomicAdd(&rad_s[nt * 16 + m], s);
    }
    __syncthreads();
    if (tid < N_OUT) atomicAdd(&rad_out[b * N_OUT + tid], rad_s[tid]);
}

// ---------------------------------------------------------------------------
__global__ void combine_k(const float* __restrict__ head_out,
                          const float* __restrict__ rad_out,
                          float* __restrict__ out)
{
    int i = blockIdx.x * 256 + threadIdx.x;
    if (i < BSZ * N_OUT) {
        float h = head_out[i], r = rad_out[i];
        out[i]               = h - r;
        out[BSZ * N_OUT + i] = h + r;
    }
}

// ---------------------------------------------------------------------------
extern "C" void kernel_launch(void* const* d_in, const int* in_sizes, int n_in,
                              void* d_out, int out_size, void* d_ws, size_t ws_size,
                              hipStream_t stream)
{
    const float* X    = (const float*)d_in[0];
    const float* eps  = (const float*)d_in[1];
    const float* Wih  = (const float*)d_in[2];
    const float* Whh  = (const float*)d_in[3];
    const float* bih  = (const float*)d_in[4];
    const float* bhh  = (const float*)d_in[5];
    const float* Wo   = (const float*)d_in[6];
    const float* bo   = (const float*)d_in[7];
    float* out = (float*)d_out;

    const size_t per_sample = (size_t)ESTRIDE * H * 2 + (size_t)N_OUT * H * 2;
    const size_t shared_b = (size_t)H * H * 4       // WhhT32
                          + (size_t)N_OUT * H * 4   // WoT32
                          + (size_t)N_IN * H * 4    // WihP
                          + (size_t)H * H * 4       // WhhP
                          + (size_t)H * H * 2       // WhhTp
                          + (size_t)T_STEPS * BSZ * H * 4                // hpX
                          + (size_t)T_STEPS * BSZ * H * 4                // radT
                          + (size_t)3 * BSZ * H * 4                      // lam/de/head_h
                          + (size_t)2 * BSZ * N_OUT * 4
                          + (size_t)T_STEPS * BSZ * 4 + 512;             // arrive
    int Bc = BSZ;
    while (Bc > 1 && (size_t)Bc * per_sample + shared_b > ws_size) Bc >>= 1;

    char* p = (char*)d_ws;
    u16* errP      = (u16*)p;   p += (size_t)Bc * ESTRIDE * H * 2;
    u16* WoTp      = (u16*)p;   p += (size_t)Bc * N_OUT * H * 2;
    u16* WhhTp     = (u16*)p;   p += (size_t)H * H * 2;
    float* WhhT32  = (float*)p; p += (size_t)H * H * 4;
    float* WoT32   = (float*)p; p += (size_t)N_OUT * H * 4;
    float* WihP    = (float*)p; p += (size_t)N_IN * H * 4;
    float* WhhP    = (float*)p; p += (size_t)H * H * 4;
    float* hpX     = (float*)p; p += (size_t)T_STEPS * BSZ * H * 4;
    float* radT    = (float*)p; p += (size_t)T_STEPS * BSZ * H * 4;
    float* lam     = (float*)p; p += (size_t)BSZ * H * 4;
    float* de      = (float*)p; p += (size_t)BSZ * H * 4;
    float* head_h  = (float*)p; p += (size_t)BSZ * H * 4;
    float* head_out= (float*)p; p += (size_t)BSZ * N_OUT * 4;
    float* rad_out = (float*)p; p += (size_t)BSZ * N_OUT * 4 + 64;
    unsigned* arrive = (unsigned*)p;

    initarr_k<<<(T_STEPS * BSZ) / 256, 256, 0, stream>>>(arrive);
    transpose_k<<<dim3(H / 32, H / 32), 256, 0, stream>>>(Whh, WhhT32, H, H);
    transpose_k<<<dim3(N_OUT / 32, H / 32), 256, 0, stream>>>(Wo, WoT32, H, N_OUT);
    packPairs_k<<<(N_IN * 128) / 256, 256, 0, stream>>>(Wih, WihP);
    packPairs_k<<<(H * 128) / 256, 256, 0, stream>>>(Whh, WhhP);
    packWT_k<<<128, 256, 0, stream>>>(WhhT32, WhhTp);

    for (int b0 = 0; b0 < BSZ; b0 += Bc) {
        prefresh_k<<<dim3(T_STEPS, Bc), 256, 0, stream>>>(
            X + (size_t)b0 * N_IN, eps + b0, Wih, WihP, bih, bhh, errP,
            radT + (size_t)b0 * H, hpX + (size_t)b0 * H);

        int Bc2 = (Bc + 1) / 2;
        loop_k<<<dim3(NSL, Bc2), 256, 0, stream>>>(
            Whh, WhhP, WhhTp, hpX, radT, errP, arrive, b0, Bc, Bc2);

        const float* hp_last  = hpX  + (size_t)(T_STEPS - 1) * BSZ * H + (size_t)b0 * H;
        const float* rad_last = radT + (size_t)(T_STEPS - 1) * BSZ * H + (size_t)b0 * H;
        tanh_final_k<<<Bc, 256, 0, stream>>>(
            hp_last, rad_last, lam + (size_t)b0 * H, de + (size_t)b0 * H,
            head_h + (size_t)b0 * H);
        packWoT_k<<<Bc, 256, 0, stream>>>(WoT32, lam + (size_t)b0 * H, WoTp);
        head_out_k<<<Bc, 64, 0, stream>>>(
            head_h + (size_t)b0 * H, de + (size_t)b0 * H, Wo, bo,
            head_out + (size_t)b0 * N_OUT, rad_out + (size_t)b0 * N_OUT);
        gemm_out_k<<<dim3(ESTRIDE / 256, Bc), 256, 0, stream>>>(
            errP, WoTp, rad_out + (size_t)b0 * N_OUT);
    }

    combine_k<<<(BSZ * N_OUT + 255) / 256, 256, 0, stream>>>(head_out, rad_out, out);
}

// Round 10
// 1635.558 us; speedup vs baseline: 1.4380x; 1.4380x over previous
//
#include <hip/hip_runtime.h>
#include <math.h>

typedef unsigned short u16;
typedef unsigned long long u64;
typedef __attribute__((ext_vector_type(8))) short bf16x8;   // MFMA A/B frag
typedef __attribute__((ext_vector_type(4))) float f32x4;    // MFMA C/D frag

#define T_STEPS 32
#define BSZ     32
#define N_IN    64
#define H       256
#define N_OUT   64
#define ESTRIDE 9984              // rows = 320*31 + 64 (final fresh block)
#define CLAMP_MIN (-2.0f)
#define CLAMP_MAX ( 2.0f)
#define GNB 16                    // gemm blocks per sample (32-row tiles)

// ---------------------------------------------------------------------------
// Fragment-packed layout "B" (8B-quad granular):
//   element (row R, k):  RT=R>>4, m=R&15, KC=k>>5, qq=(k&31)>>3, h=(k&7)>>2, v=k&3
//   u16 offset = ((RT*8+KC)*4+qq)*128 + m*8 + h*4 + v
// A/B-frag load for (RT,KC), lane(m,q): contiguous 16B at (((RT*8+KC)*4+q)<<7)+m*8.
// C^T store (operand-swapped mfma): lane's 4 acc values = 8B contiguous.
//
// Fence-free dataflow sync (r8-verified): err rows are BLOCK-PRIVATE (tile j
// owned by block j%GNB; diag tiles written by owner). Cross-block data = only
// rad/hp (device-scope atomics; read via agent-scope atomic loads). Per-sample
// arrival counters order steps. r10: diag+GEMV epilogue moved BEFORE the tile
// loop (depends only on tanh outputs) — removes it from the step's critical
// tail and hides the prologue stage-load latency under its VALU work.
// ---------------------------------------------------------------------------

__device__ inline u16 f2bf(float x) {                       // RTNE fp32->bf16
    unsigned u = __builtin_bit_cast(unsigned, x);
    unsigned r = u + 0x7FFFu + ((u >> 16) & 1u);
    return (u16)(r >> 16);
}
__device__ inline float bf2f(short s) {
    return __builtin_bit_cast(float, ((unsigned)(u16)s) << 16);
}

__device__ __forceinline__ void gl_lds16(const u16* g, u16* l) {
    __builtin_amdgcn_global_load_lds(
        (const __attribute__((address_space(1))) unsigned int*)g,
        (__attribute__((address_space(3))) unsigned int*)l,
        16, 0, 0);
}

__device__ __forceinline__ float aload(const float* p) {
    return __hip_atomic_load(p, __ATOMIC_RELAXED, __HIP_MEMORY_SCOPE_AGENT);
}

// ---------------------------------------------------------------------------
__global__ void initarr_k(unsigned* arr) {                  // zero arrival ctrs
    arr[threadIdx.x + blockIdx.x * 256] = 0u;
}

// ---------------------------------------------------------------------------
__global__ void transpose_k(const float* __restrict__ src, float* __restrict__ dst,
                            int R, int C)
{
    __shared__ float tile[32][33];
    int bi = blockIdx.y, bj = blockIdx.x;
    int r0 = threadIdx.x >> 5, c = threadIdx.x & 31;
    #pragma unroll
    for (int rr = 0; rr < 4; ++rr) {
        int r = r0 * 4 + rr;
        tile[r][c] = src[(bi * 32 + r) * C + bj * 32 + c];
    }
    __syncthreads();
    #pragma unroll
    for (int rr = 0; rr < 4; ++rr) {
        int r = r0 * 4 + rr;
        dst[(bj * 32 + r) * R + bi * 32 + c] = tile[c][r];
    }
}

// ---------------------------------------------------------------------------
// packPairs: W (R x 256 fp32) -> float2 pairs in layout-B p-order.
// ---------------------------------------------------------------------------
__global__ void packPairs_k(const float* __restrict__ W, float* __restrict__ WP)
{
    int p = blockIdx.x * 256 + threadIdx.x;
    int vb = (p & 1) * 2, hh = (p >> 1) & 1, m = (p >> 2) & 15, qq = (p >> 6) & 3;
    int KC = (p >> 8) & 7, RT = p >> 11;
    int i = RT * 16 + m, k = KC * 32 + qq * 8 + hh * 4 + vb;
    ((float2*)WP)[p] = make_float2(W[(size_t)i * H + k], W[(size_t)i * H + k + 1]);
}

// ---------------------------------------------------------------------------
// packWT: WhhT32 (256x256 fp32) -> bf16 layout-B (static, no lam). grid 128x256.
// ---------------------------------------------------------------------------
__global__ void packWT_k(const float* __restrict__ WT32, u16* __restrict__ WTp)
{
    int p = blockIdx.x * 256 + threadIdx.x;     // p < 32768
    int vb = (p & 1) * 2, hh = (p >> 1) & 1, m = (p >> 2) & 15, qq = (p >> 6) & 3;
    int KC = (p >> 8) & 7, RT = p >> 11;
    int n = RT * 16 + m, k = KC * 32 + qq * 8 + hh * 4 + vb;
    *(unsigned*)&WTp[2 * p] =
          (unsigned)f2bf(WT32[(size_t)n * H + k])
        | ((unsigned)f2bf(WT32[(size_t)n * H + k + 1]) << 16);
}

// ---------------------------------------------------------------------------
// prefresh: fresh rows (rho_t * Wih) for ALL t + fresh-rad baseline + head
// baseline hpX[t] = bias + hx_t @ Wih. grid (T_STEPS, Bc).
// ---------------------------------------------------------------------------
__global__ __launch_bounds__(256) void prefresh_k(
    const float* __restrict__ X, const float* __restrict__ eps,
    const float* __restrict__ Wih, const float* __restrict__ WihP,
    const float* __restrict__ bih, const float* __restrict__ bhh,
    u16* __restrict__ err, float* __restrict__ radT, float* __restrict__ hpX)
{
    __shared__ float rho_s[N_IN], hx_s[N_IN];
    const int t = blockIdx.x, bi = blockIdx.y, tid = threadIdx.x;
    if (tid < N_IN) {
        float x = X[((size_t)t * BSZ + bi) * N_IN + tid], e = eps[bi];
        float lo = fmaxf(x - e, CLAMP_MIN), up = fminf(x + e, CLAMP_MAX);
        rho_s[tid] = 0.5f * (up - lo);
        hx_s[tid]  = 0.5f * (up + lo);
    }
    __syncthreads();

    float s = 0.f, acc = bih[tid] + bhh[tid];
    #pragma unroll 8
    for (int i = 0; i < N_IN; ++i) {
        float w = Wih[(size_t)i * H + tid];
        s   += fabsf(rho_s[i]) * fabsf(w);
        acc += hx_s[i] * w;
    }
    radT[(size_t)t * BSZ * H + (size_t)bi * H + tid] = s;
    hpX [(size_t)t * BSZ * H + (size_t)bi * H + tid] = acc;

    u16* dst = err + (size_t)bi * ESTRIDE * H + (size_t)(20 * t) * 4096; // row 320t
    const float2* wp = (const float2*)WihP;
    #pragma unroll 4
    for (int iter = 0; iter < 32; ++iter) {
        int p = iter * 256 + tid;
        int i = (p >> 11) * 16 + ((p >> 2) & 15);
        float2 w = wp[p];
        float rho = rho_s[i];
        *(unsigned*)&dst[2 * p] =
            (unsigned)f2bf(rho * w.x) | ((unsigned)f2bf(rho * w.y) << 16);
    }
}

// ---------------------------------------------------------------------------
// loop_k: PERSISTENT t-loop, fence-free sync (r8 base). grid (GNB, Bc) = 512
// blocks = 2/CU co-resident. r10 change: diag rows + rad/head GEMV run BEFORE
// the GEMM tile loop (they depend only on tanh outputs); the step tail is now
// just {drain, racc reduce, publish}, and the pre-loop vmcnt(0) waits on
// stage loads that already flew under the diag/GEMV work.
// ---------------------------------------------------------------------------
__global__ __launch_bounds__(256, 2) void loop_k(
    const float* __restrict__ Whh, const float* __restrict__ WhhP,
    const u16* __restrict__ WhhTp,
    float* __restrict__ hpX, float* __restrict__ radT,
    u16* __restrict__ err, unsigned* __restrict__ arrive, int b0)
{
    __shared__ u16 sbuf[4][8192];            // 4 x 16KB tile ring
    __shared__ float lam_s[H], de_s[H], hh_s[H];
    const int bx = blockIdx.x, b = blockIdx.y, tid = threadIdx.x;
    const int babs = b0 + b;
    u16* errB = err + (size_t)b * ESTRIDE * H;
    const int wave = tid >> 6, lane = tid & 63;
    const int m = lane & 15, q = lane >> 4;

    #pragma unroll 1
    for (int t = 1; t < T_STEPS; ++t) {
        const int E_old = t * (N_IN + H);
        const int ntiles = (E_old - H) >> 5;             // 32-row tiles = 10t-8
        const float* hpp  = hpX  + (size_t)(t - 1) * BSZ * H + (size_t)babs * H;
        float*       hpn  = hpX  + (size_t)t       * BSZ * H + (size_t)babs * H;
        const float* radp = radT + (size_t)(t - 1) * BSZ * H + (size_t)babs * H;
        float*       radn = radT + (size_t)t       * BSZ * H + (size_t)babs * H;
        const bool gem = (bx < ntiles);

        // issue own-tile stages + B-slab loads BEFORE the sync spin:
        // block-private / read-only data only.
        if (gem) {
            #pragma unroll
            for (int j = 0; j < 3; ++j) {
                int tj = bx + j * GNB;
                if (tj < ntiles) {
                    const u16* g = errB + (size_t)tj * 8192;
                    #pragma unroll
                    for (int r = 0; r < 4; ++r)
                        gl_lds16(g + r * 2048 + tid * 8,
                                 &sbuf[j][r * 2048 + wave * 512]);
                }
            }
        }
        bf16x8 bf[4][8];
        if (gem) {
            #pragma unroll
            for (int nt = 0; nt < 4; ++nt)
                #pragma unroll
                for (int kc = 0; kc < 8; ++kc)
                    bf[nt][kc] = *(const bf16x8*)
                        &WhhTp[(size_t)(((((wave * 4 + nt) * 8 + kc) * 4 + q) << 7) + m * 8)];
        }

        // wait for step t-1's 16 producer blocks of THIS sample (t>=2).
        if (t > 1) {
            if (tid == 0) {
                const unsigned* a = &arrive[(t - 1) * BSZ + babs];
                while (__hip_atomic_load(a, __ATOMIC_RELAXED,
                                         __HIP_MEMORY_SCOPE_AGENT) < (unsigned)GNB)
                    __builtin_amdgcn_s_sleep(2);
            }
            __builtin_amdgcn_s_barrier();    // raw: vm loads stay in flight
        }

        { // coherent read of rad/hp (atomic loads: coherence point) + tanh
            float hd = aload(&hpp[tid]), rv = aload(&radp[tid]);
            float lo = hd - rv, up = hd + rv;
            float tl = tanhf(lo), tu = tanhf(up);
            float la = fminf(1.f - tl * tl, 1.f - tu * tu);
            float mu = 0.5f * (tu + tl - la * (up + lo));
            float dd = 0.5f * (tu - tl - la * (up - lo));
            lam_s[tid] = la;
            de_s[tid]  = dd;
            hh_s[tid]  = la * hd + mu;
        }
        asm volatile("s_waitcnt lgkmcnt(0)" ::: "memory");
        __builtin_amdgcn_s_barrier();        // LDS visible (vm loads flying)

        // ---- moved-up epilogue: diag tiles (owner) + rad/head GEMV ----
        // Depends only on de_s/hh_s. Its VALU + latency work covers the
        // prologue stage loads' flight; diag tiles (>= ntiles) are disjoint
        // from GEMM tiles (< ntiles) and block-private.
        {
            const int dtile0 = 10 * t - 8;
            const float2* wp = (const float2*)WhhP;
            #pragma unroll
            for (int i = 0; i < 8; ++i) {
                int dt = dtile0 + i;
                if ((dt & 15) == bx) {
                    #pragma unroll
                    for (int rt2 = 0; rt2 < 2; ++rt2) {
                        int RTw = i * 2 + rt2;           // Whh row-tile
                        u16* dst2 = errB + (size_t)(dt * 2 + rt2) * 4096;
                        const float2* wp2 = wp + (size_t)RTw * 2048;
                        #pragma unroll
                        for (int iter = 0; iter < 8; ++iter) {
                            int p = iter * 256 + tid;
                            int mm = (p >> 2) & 15;
                            float dv = de_s[RTw * 16 + mm];
                            float2 w = wp2[p];
                            *(unsigned*)&dst2[2 * p] =
                                (unsigned)f2bf(dv * w.x) | ((unsigned)f2bf(dv * w.y) << 16);
                        }
                    }
                }
            }
            float ss = 0.f, hacc = 0.f;
            #pragma unroll
            for (int ii = 0; ii < 16; ++ii) {
                int i = bx * 16 + ii;
                float w = Whh[(size_t)i * H + tid];
                ss   += fabsf(de_s[i]) * fabsf(w);
                hacc += hh_s[i] * w;
            }
            atomicAdd(&radn[tid], ss);
            atomicAdd(&hpn[tid], hacc);
        }

        if (gem) {
            // fold lam into B-frags in-register (one-time per block per step)
            #pragma unroll
            for (int nt = 0; nt < 4; ++nt)
                #pragma unroll
                for (int kc = 0; kc < 8; ++kc) {
                    const int k0 = kc * 32 + q * 8;
                    float4 la = *(const float4*)&lam_s[k0];
                    float4 lb = *(const float4*)&lam_s[k0 + 4];
                    bf16x8 w = bf[nt][kc], f;
                    f[0] = (short)f2bf(bf2f(w[0]) * la.x);
                    f[1] = (short)f2bf(bf2f(w[1]) * la.y);
                    f[2] = (short)f2bf(bf2f(w[2]) * la.z);
                    f[3] = (short)f2bf(bf2f(w[3]) * la.w);
                    f[4] = (short)f2bf(bf2f(w[4]) * lb.x);
                    f[5] = (short)f2bf(bf2f(w[5]) * lb.y);
                    f[6] = (short)f2bf(bf2f(w[6]) * lb.z);
                    f[7] = (short)f2bf(bf2f(w[7]) * lb.w);
                    bf[nt][kc] = f;
                }

            float racc[16];
            #pragma unroll
            for (int i = 0; i < 16; ++i) racc[i] = 0.f;

            // prologue stages long arrived (covered by diag/GEMV work)
            asm volatile("s_waitcnt vmcnt(0)" ::: "memory");
            __builtin_amdgcn_s_barrier();

            int cur = 0;
            for (int tile = bx; tile < ntiles; tile += GNB) {
                int pf = tile + 3 * GNB;
                if (pf < ntiles) {           // stage 3 tiles ahead
                    const u16* g = errB + (size_t)pf * 8192;
                    #pragma unroll
                    for (int r = 0; r < 4; ++r)
                        gl_lds16(g + r * 2048 + tid * 8,
                                 &sbuf[(cur + 3) & 3][r * 2048 + wave * 512]);
                }

                f32x4 acc[2][4];
                #pragma unroll
                for (int i = 0; i < 2; ++i)
                    #pragma unroll
                    for (int c = 0; c < 4; ++c) acc[i][c] = (f32x4){0.f, 0.f, 0.f, 0.f};

                #pragma unroll
                for (int kc = 0; kc < 8; ++kc) {
                    bf16x8 af[2];
                    #pragma unroll
                    for (int rt = 0; rt < 2; ++rt)
                        af[rt] = *(const bf16x8*)
                            &sbuf[cur][(((rt * 8 + kc) * 4 + q) << 7) + m * 8];
                    #pragma unroll
                    for (int nt = 0; nt < 4; ++nt)
                        #pragma unroll
                        for (int rt = 0; rt < 2; ++rt)   // A=WT, B=err -> C^T
                            acc[rt][nt] = __builtin_amdgcn_mfma_f32_16x16x32_bf16(
                                bf[nt][kc], af[rt], acc[rt][nt], 0, 0, 0);
                }

                // C^T store: lane holds err-row r = rt*16+m, n = NT*16+q*4+v
                #pragma unroll
                for (int rt = 0; rt < 2; ++rt) {
                    const size_t rowbase = (size_t)(tile * 2 + rt) * 4096;
                    #pragma unroll
                    for (int nt = 0; nt < 4; ++nt) {
                        f32x4 v = acc[rt][nt];
                        racc[nt * 4 + 0] += fabsf(v[0]);
                        racc[nt * 4 + 1] += fabsf(v[1]);
                        racc[nt * 4 + 2] += fabsf(v[2]);
                        racc[nt * 4 + 3] += fabsf(v[3]);
                        unsigned lo = (unsigned)f2bf(v[0]) | ((unsigned)f2bf(v[1]) << 16);
                        unsigned hi = (unsigned)f2bf(v[2]) | ((unsigned)f2bf(v[3]) << 16);
                        const int NT  = wave * 4 + nt;
                        const int kcs = NT >> 1;
                        const int qq  = (NT & 1) * 2 + (q >> 1);
                        const size_t off16 = rowbase
                            + (size_t)(((kcs * 4 + qq) << 7) + m * 8 + (q & 1) * 4);
                        *(u64*)&errB[off16] = ((u64)hi << 32) | lo;
                    }
                }
                // vmcnt(32): newest 32 = stores_j(8)+stage_j(4)+stores_{j-1}(8)
                // +stage_{j-1}(4)+stores_{j-2}(8); drains exactly stage_{j-3}
                // — the buffer consumed NEXT iter; 2 iters of stage in flight.
                asm volatile("s_waitcnt vmcnt(32)" ::: "memory");
                __builtin_amdgcn_s_barrier();
                cur = (cur + 1) & 3;
            }

            // rad: reduce over 16 m-lanes, one atomic per n from m==0 lanes
            #pragma unroll
            for (int i = 0; i < 16; ++i) {
                float v = racc[i];
                v += __shfl_xor(v, 1);
                v += __shfl_xor(v, 2);
                v += __shfl_xor(v, 4);
                v += __shfl_xor(v, 8);
                if (m == 0) {
                    int nt = i >> 2, vv = i & 3;
                    atomicAdd(&radn[wave * 64 + nt * 16 + q * 4 + vv], v);
                }
            }
        }

        // publish: all waves' VM ops (stores + atomics) acked, then arrive++.
        asm volatile("s_waitcnt vmcnt(0)" ::: "memory");
        __syncthreads();
        if (tid == 0)
            __hip_atomic_fetch_add(&arrive[t * BSZ + babs], 1u,
                                   __ATOMIC_RELAXED, __HIP_MEMORY_SCOPE_AGENT);
    }
}

// ---------------------------------------------------------------------------
__global__ __launch_bounds__(256) void tanh_final_k(
    const float* __restrict__ hp, const float* __restrict__ rad,
    float* __restrict__ lam, float* __restrict__ de, float* __restrict__ head_h)
{
    const int b = blockIdx.x, h = threadIdx.x;
    float hd = hp[b * H + h], r = rad[b * H + h];
    float l = hd - r, u = hd + r;
    float tl = tanhf(l), tu = tanhf(u);
    float la = fminf(1.f - tl * tl, 1.f - tu * tu);
    float mu = 0.5f * (tu + tl - la * (u + l));
    float dd = 0.5f * (tu - tl - la * (u - l));
    lam[b * H + h] = la;
    de[b * H + h]  = dd;
    head_h[b * H + h] = la * hd + mu;
}

// ---------------------------------------------------------------------------
// pack WoT frag-packed (layout B), lam folded. grid Bc x 256.
// ---------------------------------------------------------------------------
__global__ __launch_bounds__(256) void packWoT_k(
    const float* __restrict__ WoT32, const float* __restrict__ lam,
    u16* __restrict__ WoTp)
{
    const int b = blockIdx.x, tid = threadIdx.x;
    __shared__ float lam_s[H];
    lam_s[tid] = lam[b * H + tid];
    __syncthreads();
    u16* dst = WoTp + (size_t)b * N_OUT * H;
    #pragma unroll 4
    for (int iter = 0; iter < 32; ++iter) {
        int p = iter * 256 + tid;
        int vb = (p & 1) * 2, hh = (p >> 1) & 1, m = (p >> 2) & 15, qq = (p >> 6) & 3;
        int KC = (p >> 8) & 7, RT = p >> 11;   // RT < 4
        int n = RT * 16 + m, k = KC * 32 + qq * 8 + hh * 4 + vb;
        *(unsigned*)&dst[2 * p] =
              (unsigned)f2bf(lam_s[k]     * WoT32[(size_t)n * H + k])
            | ((unsigned)f2bf(lam_s[k + 1] * WoT32[(size_t)n * H + k + 1]) << 16);
    }
}

// ---------------------------------------------------------------------------
__global__ void head_out_k(
    const float* __restrict__ head_h, const float* __restrict__ de,
    const float* __restrict__ Wo, const float* __restrict__ bo,
    float* __restrict__ head_out, float* __restrict__ rad_out)
{
    const int b = blockIdx.x, o = threadIdx.x;
    float acc = bo[o], accR = 0.f;
    #pragma unroll 4
    for (int j = 0; j < H; ++j) {
        float w = Wo[j * N_OUT + o];
        acc  += head_h[b * H + j] * w;
        accR += fabsf(de[b * H + j] * w);
    }
    head_out[b * N_OUT + o] = acc;
    rad_out[b * N_OUT + o]  = accR;
}

// ---------------------------------------------------------------------------
// final radius: rad_out += sum_rows |err @ WoTp^T| over all ESTRIDE rows.
// ---------------------------------------------------------------------------
__global__ __launch_bounds__(256) void gemm_out_k(
    const u16* __restrict__ err, const u16* __restrict__ WoTp,
    float* __restrict__ rad_out)
{
    __shared__ float rad_s[N_OUT];
    const int b = blockIdx.y, row0 = blockIdx.x * 256, tid = threadIdx.x;
    const int wave = tid >> 6, lane = tid & 63;
    const int m = lane & 15, q = lane >> 4;
    const u16* errB = err + (size_t)b * ESTRIDE * H;
    const u16* Wb   = WoTp + (size_t)b * N_OUT * H;

    if (tid < N_OUT) rad_s[tid] = 0.f;
    __syncthreads();

    f32x4 acc[4][4];
    #pragma unroll
    for (int i = 0; i < 4; ++i)
        #pragma unroll
        for (int c = 0; c < 4; ++c) acc[i][c] = (f32x4){0.f, 0.f, 0.f, 0.f};

    const int tile0 = (row0 >> 4) + wave * 4;
    #pragma unroll
    for (int kc = 0; kc < 8; ++kc) {
        bf16x8 af[4], bw[4];
        #pragma unroll
        for (int rt = 0; rt < 4; ++rt)
            af[rt] = *(const bf16x8*)
                &errB[(size_t)(((((tile0 + rt) * 8 + kc) * 4 + q) << 7) + m * 8)];
        #pragma unroll
        for (int nt = 0; nt < 4; ++nt)
            bw[nt] = *(const bf16x8*)
                &Wb[(size_t)((((nt * 8 + kc) * 4 + q) << 7) + m * 8)];
        #pragma unroll
        for (int nt = 0; nt < 4; ++nt)
            #pragma unroll
            for (int rt = 0; rt < 4; ++rt)
                acc[rt][nt] = __builtin_amdgcn_mfma_f32_16x16x32_bf16(
                    af[rt], bw[nt], acc[rt][nt], 0, 0, 0);
    }
    #pragma unroll
    for (int nt = 0; nt < 4; ++nt) {
        float s = 0.f;
        #pragma unroll
        for (int rt = 0; rt < 4; ++rt)
            #pragma unroll
            for (int r = 0; r < 4; ++r) s += fabsf(acc[rt][nt][r]);
        atomicAdd(&rad_s[nt * 16 + m], s);
    }
    __syncthreads();
    if (tid < N_OUT) atomicAdd(&rad_out[b * N_OUT + tid], rad_s[tid]);
}

// ---------------------------------------------------------------------------
__global__ void combine_k(const float* __restrict__ head_out,
                          const float* __restrict__ rad_out,
                          float* __restrict__ out)
{
    int i = blockIdx.x * 256 + threadIdx.x;
    if (i < BSZ * N_OUT) {
        float h = head_out[i], r = rad_out[i];
        out[i]               = h - r;
        out[BSZ * N_OUT + i] = h + r;
    }
}

// ---------------------------------------------------------------------------
extern "C" void kernel_launch(void* const* d_in, const int* in_sizes, int n_in,
                              void* d_out, int out_size, void* d_ws, size_t ws_size,
                              hipStream_t stream)
{
    const float* X    = (const float*)d_in[0];
    const float* eps  = (const float*)d_in[1];
    const float* Wih  = (const float*)d_in[2];
    const float* Whh  = (const float*)d_in[3];
    const float* bih  = (const float*)d_in[4];
    const float* bhh  = (const float*)d_in[5];
    const float* Wo   = (const float*)d_in[6];
    const float* bo   = (const float*)d_in[7];
    float* out = (float*)d_out;

    const size_t per_sample = (size_t)ESTRIDE * H * 2 + (size_t)N_OUT * H * 2;
    const size_t shared_b = (size_t)H * H * 4       // WhhT32
                          + (size_t)N_OUT * H * 4   // WoT32
                          + (size_t)N_IN * H * 4    // WihP
                          + (size_t)H * H * 4       // WhhP
                          + (size_t)H * H * 2       // WhhTp
                          + (size_t)T_STEPS * BSZ * H * 4                // hpX
                          + (size_t)T_STEPS * BSZ * H * 4                // radT
                          + (size_t)3 * BSZ * H * 4                      // lam/de/head_h
                          + (size_t)2 * BSZ * N_OUT * 4
                          + (size_t)T_STEPS * BSZ * 4 + 512;             // arrive
    int Bc = BSZ;
    while (Bc > 1 && (size_t)Bc * per_sample + shared_b > ws_size) Bc >>= 1;

    char* p = (char*)d_ws;
    u16* errP      = (u16*)p;   p += (size_t)Bc * ESTRIDE * H * 2;
    u16* WoTp      = (u16*)p;   p += (size_t)Bc * N_OUT * H * 2;
    u16* WhhTp     = (u16*)p;   p += (size_t)H * H * 2;
    float* WhhT32  = (float*)p; p += (size_t)H * H * 4;
    float* WoT32   = (float*)p; p += (size_t)N_OUT * H * 4;
    float* WihP    = (float*)p; p += (size_t)N_IN * H * 4;
    float* WhhP    = (float*)p; p += (size_t)H * H * 4;
    float* hpX     = (float*)p; p += (size_t)T_STEPS * BSZ * H * 4;
    float* radT    = (float*)p; p += (size_t)T_STEPS * BSZ * H * 4;
    float* lam     = (float*)p; p += (size_t)BSZ * H * 4;
    float* de      = (float*)p; p += (size_t)BSZ * H * 4;
    float* head_h  = (float*)p; p += (size_t)BSZ * H * 4;
    float* head_out= (float*)p; p += (size_t)BSZ * N_OUT * 4;
    float* rad_out = (float*)p; p += (size_t)BSZ * N_OUT * 4 + 64;
    unsigned* arrive = (unsigned*)p;

    initarr_k<<<(T_STEPS * BSZ) / 256, 256, 0, stream>>>(arrive);
    transpose_k<<<dim3(H / 32, H / 32), 256, 0, stream>>>(Whh, WhhT32, H, H);
    transpose_k<<<dim3(N_OUT / 32, H / 32), 256, 0, stream>>>(Wo, WoT32, H, N_OUT);
    packPairs_k<<<(N_IN * 128) / 256, 256, 0, stream>>>(Wih, WihP);
    packPairs_k<<<(H * 128) / 256, 256, 0, stream>>>(Whh, WhhP);
    packWT_k<<<128, 256, 0, stream>>>(WhhT32, WhhTp);

    for (int b0 = 0; b0 < BSZ; b0 += Bc) {
        prefresh_k<<<dim3(T_STEPS, Bc), 256, 0, stream>>>(
            X + (size_t)b0 * N_IN, eps + b0, Wih, WihP, bih, bhh, errP,
            radT + (size_t)b0 * H, hpX + (size_t)b0 * H);

        // persistent fence-free t-loop (normal launch, co-resident grid)
        loop_k<<<dim3(GNB, Bc), 256, 0, stream>>>(
            Whh, WhhP, WhhTp, hpX, radT, errP, arrive, b0);

        const float* hp_last  = hpX  + (size_t)(T_STEPS - 1) * BSZ * H + (size_t)b0 * H;
        const float* rad_last = radT + (size_t)(T_STEPS - 1) * BSZ * H + (size_t)b0 * H;
        tanh_final_k<<<Bc, 256, 0, stream>>>(
            hp_last, rad_last, lam + (size_t)b0 * H, de + (size_t)b0 * H,
            head_h + (size_t)b0 * H);
        packWoT_k<<<Bc, 256, 0, stream>>>(WoT32, lam + (size_t)b0 * H, WoTp);
        head_out_k<<<Bc, 64, 0, stream>>>(
            head_h + (size_t)b0 * H, de + (size_t)b0 * H, Wo, bo,
            head_out + (size_t)b0 * N_OUT, rad_out + (size_t)b0 * N_OUT);
        gemm_out_k<<<dim3(ESTRIDE / 256, Bc), 256, 0, stream>>>(
            errP, WoTp, rad_out + (size_t)b0 * N_OUT);
    }

    combine_k<<<(BSZ * N_OUT + 255) / 256, 256, 0, stream>>>(head_out, rad_out, out);
}